// Round 1
// baseline (233.175 us; speedup 1.0000x reference)
//
#include <hip/hip_runtime.h>
#include <hip/hip_bf16.h>
#include <stdint.h>

// Problem constants (B=4, L=4096, D=1024, K=3)
#define B_SZ   4
#define L_SEQ  4096
#define D_DIM  1024
#define M_TOT  (B_SZ * L_SEQ)   // 16384

typedef __bf16 bf16;
typedef __attribute__((ext_vector_type(8))) __bf16 bf16x8;
typedef __attribute__((ext_vector_type(4))) float   f32x4;

// ---------------------------------------------------------------------------
// Single fused kernel: depthwise conv (K=3, causal) + bf16 cast happens INSIDE
// the GEMM's A-staging; w_pw fp32->bf16 happens inside B-staging. No y buffer,
// no cvt kernel, one launch.
//
// GEMM: out[m][n] = sum_k conv(x)[m][k] * w_pw[n][k] + b_pw[n]
// M=16384, N=1024, K=1024. BM=BN=128, BK=32, 4 waves, double-buffered LDS,
// one barrier per K-step (identical schedule to the previous gemm_bt_kernel).
//
// A-staging (reg-staged, replaces global_load_lds):
//   thread = (cg = t&7 -> 4 channels, rg = t>>3 -> 4 rows). Loads 6 x-rows
//   (4 out + 2 causal halo; halo rows always exist in global x because batch
//   boundaries align with BM tiles — zeroed only when m0%4096==0 && rg==0),
//   3 fp32 FMA/elem with per-channel w_dw/b_dw (b_dw folded as FMA seed),
//   cvt->bf16, ds_write_b64. B-staging: 4 float4 of w_pw, cvt, ds_write_b64.
//
// LDS swizzle (write AND read, identity overall):
//   addr(row,ch) = row*64 + ((g ^ ((row>>1)&3))<<4) + (ch&7)*2,  g = ch>>3
//   addr ^= ((row>>2)&1) << 6
// The chunk-XOR is the proven frag-read swizzle; the bit-6 XOR (row-LSB addr
// bit flipped by row bit2, bijective) splits a write instruction's lanes
// across both 16-bank halves: ds_write_b64 goes 8-way -> 2-way (free),
// ds_read_b128 frags stay <=2-way per 16-lane phase.
//
// GRID (m=x fastest, n=y): XCD = mb%8, so all 8 n-blocks of an m-block share
// an XCD => x-tile fetched ~once from HBM, L2-hits for the other 7 (the same
// property that kept A at 1x fetch before).
// ---------------------------------------------------------------------------
#define BM 128
#define BN 128
#define BK 32
#define EP_ROWP 68   // fp32 per padded epilogue row

__global__ __launch_bounds__(256) void fused_dwpw_gemm(
    const float* __restrict__ x, const float* __restrict__ w_dw,
    const float* __restrict__ b_dw, const float* __restrict__ w_pw,
    const float* __restrict__ b_pw, float* __restrict__ C) {
  __shared__ __align__(16) char smem[32768];
  // buf p: A at p*16384, B at p*16384 + 8192

  const int t    = threadIdx.x;
  const int m0   = blockIdx.x * BM;   // grid.x = 128 (m) — fastest
  const int n0   = blockIdx.y * BN;   // grid.y = 8   (n)
  const int lane = t & 63;
  const int wv   = t >> 6;
  const int wm   = (wv >> 1) * 64;
  const int wn   = (wv & 1) * 64;
  const int lrow = lane & 15;
  const int q    = lane >> 4;

  // --- staging geometry ---
  const int cg = t & 7;        // channel group (4 ch)
  const int rg = t >> 3;       // row group (4 rows), 0..31
  const int c4 = cg * 4;
  const int r0 = rg * 4;

  // swizzled LDS write offsets for rows r0..r0+3 (same for A and B tiles)
  unsigned wr[4];
#pragma unroll
  for (int j = 0; j < 4; ++j) {
    int row = r0 + j;
    unsigned a = (unsigned)(row * 64) +
                 ((((unsigned)(cg >> 1)) ^ ((unsigned)((row >> 1) & 3))) << 4) +
                 ((unsigned)(cg & 1) << 3);
    a ^= ((unsigned)((row >> 2) & 1)) << 6;
    wr[j] = a;
  }
  // swizzled frag read offsets
  unsigned ra[4], rb[4];
#pragma unroll
  for (int i = 0; i < 4; ++i) {
    int mrow = wm + i * 16 + lrow;
    unsigned a = (unsigned)(mrow * 64) +
                 (((unsigned)q ^ (unsigned)((mrow >> 1) & 3)) << 4);
    a ^= ((unsigned)((mrow >> 2) & 1)) << 6;
    ra[i] = a;
    int nrow = wn + i * 16 + lrow;
    unsigned b2 = (unsigned)(nrow * 64) +
                  (((unsigned)q ^ (unsigned)((nrow >> 1) & 3)) << 4);
    b2 ^= ((unsigned)((nrow >> 2) & 1)) << 6;
    rb[i] = b2;
  }

  // causal edge: rows m0-2, m0-1 are zero only at a batch start (m0%4096==0)
  const bool edge = (r0 == 0) && ((m0 & (L_SEQ - 1)) == 0);
  const float* xbase = x + (size_t)(m0 + r0 - 2) * D_DIM + c4;  // formed, deref guarded
  const float* bbase = w_pw + (size_t)(n0 + r0) * D_DIM + c4;

  f32x4 acc[4][4] = {};

  float4 xa[6], bw4[4], wwa, wwb, wwc, bv;

  auto issue = [&](int k0) {
    const float4 zero = make_float4(0.f, 0.f, 0.f, 0.f);
    const float* xp = xbase + k0;
    xa[0] = edge ? zero : *(const float4*)(xp);
    xa[1] = edge ? zero : *(const float4*)(xp + D_DIM);
#pragma unroll
    for (int j = 2; j < 6; ++j) xa[j] = *(const float4*)(xp + (size_t)j * D_DIM);
    const float* bp = bbase + k0;
#pragma unroll
    for (int j = 0; j < 4; ++j) bw4[j] = *(const float4*)(bp + (size_t)j * D_DIM);
    // per-channel dw weights (12 contiguous floats) + bias; L2-hot after first use
    const float* wp = w_dw + (size_t)(k0 + c4) * 3;
    wwa = *(const float4*)(wp);      // d0:k0,k1,k2  d1:k0
    wwb = *(const float4*)(wp + 4);  // d1:k1,k2     d2:k0,k1
    wwc = *(const float4*)(wp + 8);  // d2:k2        d3:k0,k1,k2
    bv  = *(const float4*)(b_dw + k0 + c4);
  };

  auto convert_store = [&](int p) {
    char* Ab = smem + p * 16384;
    char* Bb = Ab + 8192;
#pragma unroll
    for (int j = 0; j < 4; ++j) {
      float4 x2 = xa[j], x1 = xa[j + 1], x0 = xa[j + 2];
      float a0 = fmaf(x2.x, wwa.x, fmaf(x1.x, wwa.y, fmaf(x0.x, wwa.z, bv.x)));
      float a1 = fmaf(x2.y, wwa.w, fmaf(x1.y, wwb.x, fmaf(x0.y, wwb.y, bv.y)));
      float a2 = fmaf(x2.z, wwb.z, fmaf(x1.z, wwb.w, fmaf(x0.z, wwc.x, bv.z)));
      float a3 = fmaf(x2.w, wwc.y, fmaf(x1.w, wwc.z, fmaf(x0.w, wwc.w, bv.w)));
      union { bf16 h[4]; int2 v; } o;
      o.h[0] = (bf16)a0; o.h[1] = (bf16)a1; o.h[2] = (bf16)a2; o.h[3] = (bf16)a3;
      *(int2*)(Ab + wr[j]) = o.v;
    }
#pragma unroll
    for (int j = 0; j < 4; ++j) {
      union { bf16 h[4]; int2 v; } o;
      o.h[0] = (bf16)bw4[j].x; o.h[1] = (bf16)bw4[j].y;
      o.h[2] = (bf16)bw4[j].z; o.h[3] = (bf16)bw4[j].w;
      *(int2*)(Bb + wr[j]) = o.v;
    }
  };

  // prologue: stage tile 0 (latency exposed once)
  issue(0);
  convert_store(0);
  __syncthreads();

  for (int it = 0; it < D_DIM / BK; ++it) {
    // issue next tile's global loads EARLY: latency hides under frag reads+MFMA
    if (it + 1 < D_DIM / BK) issue((it + 1) * BK);

    const char* Ab = smem + (it & 1) * 16384;
    const char* Bb = Ab + 8192;
    bf16x8 af[4], bfr[4];
#pragma unroll
    for (int i = 0; i < 4; ++i) {
      af[i]  = *(const bf16x8*)(Ab + ra[i]);
      bfr[i] = *(const bf16x8*)(Bb + rb[i]);
    }
#pragma unroll
    for (int i = 0; i < 4; ++i)
#pragma unroll
      for (int j = 0; j < 4; ++j)
        acc[i][j] = __builtin_amdgcn_mfma_f32_16x16x32_bf16(af[i], bfr[j], acc[i][j], 0, 0, 0);

    // conv + cvt + write into the OTHER buffer (read in it+1 after the barrier;
    // its previous readers finished before the it-1 end barrier — no race)
    if (it + 1 < D_DIM / BK) convert_store((it + 1) & 1);
    __syncthreads();
  }

  // --- epilogue: per-wave LDS transpose, then coalesced float4 stores ---
  float* ep = (float*)smem + (size_t)wv * (16 * EP_ROWP);  // wave-private

  float bvj[4];
#pragma unroll
  for (int j = 0; j < 4; ++j) bvj[j] = b_pw[n0 + wn + j * 16 + lrow];

#pragma unroll
  for (int i = 0; i < 4; ++i) {
#pragma unroll
    for (int j = 0; j < 4; ++j)
#pragma unroll
      for (int r = 0; r < 4; ++r)
        ep[(q * 4 + r) * EP_ROWP + j * 16 + lrow] = acc[i][j][r] + bvj[j];
    // wave-private region: in-wave DS program order suffices, no barrier
#pragma unroll
    for (int it2 = 0; it2 < 4; ++it2) {
      int flat = it2 * 64 + lane;
      int row  = flat >> 4;
      int c16  = flat & 15;
      float4 v = *(const float4*)(ep + row * EP_ROWP + c16 * 4);
      int gm = m0 + wm + i * 16 + row;
      int gn = n0 + wn + c16 * 4;
      *(float4*)(C + (size_t)gm * D_DIM + gn) = v;
    }
  }
}

extern "C" void kernel_launch(void* const* d_in, const int* in_sizes, int n_in,
                              void* d_out, int out_size, void* d_ws, size_t ws_size,
                              hipStream_t stream) {
  (void)in_sizes; (void)n_in; (void)out_size; (void)d_ws; (void)ws_size;
  const float* x    = (const float*)d_in[0];
  const float* w_dw = (const float*)d_in[1];
  const float* b_dw = (const float*)d_in[2];
  const float* w_pw = (const float*)d_in[3];
  const float* b_pw = (const float*)d_in[4];
  float* out = (float*)d_out;

  dim3 grid(M_TOT / BM, D_DIM / BN);   // (128, 8): m fastest => XCD = mb%8
  fused_dwpw_gemm<<<grid, 256, 0, stream>>>(x, w_dw, b_dw, w_pw, b_pw, out);
}

// Round 2
// 155.371 us; speedup vs baseline: 1.5008x; 1.5008x over previous
//
#include <hip/hip_runtime.h>
#include <hip/hip_bf16.h>
#include <stdint.h>

// Problem constants (B=4, L=4096, D=1024, K=3)
#define B_SZ   4
#define L_SEQ  4096
#define D_DIM  1024
#define M_TOT  (B_SZ * L_SEQ)   // 16384

typedef __bf16 bf16;
typedef __attribute__((ext_vector_type(8))) __bf16 bf16x8;
typedef __attribute__((ext_vector_type(4))) float   f32x4;

#define GLOAD_LDS16(g, l)                                                     \
  __builtin_amdgcn_global_load_lds(                                           \
      (const __attribute__((address_space(1))) void*)(g),                     \
      (__attribute__((address_space(3))) void*)(l), 16, 0, 0)

// ---------------------------------------------------------------------------
// Kernel 1 (VERBATIM round-0, proven): causal depthwise conv (K=3) + bf16
// cast. block = (batch, 16-row l-chunk), thread = 4 channels. Blocks >=
// M_TOT/16 do w_pw fp32->bf16 instead (bf16 B is load-bearing: keeps the
// GEMM's B operand at 2MB so it stays XCD-L2-resident).
// ---------------------------------------------------------------------------
__global__ __launch_bounds__(256) void dw_bf16_kernel(
    const float* __restrict__ x, const float* __restrict__ w_dw,
    const float* __restrict__ b_dw, bf16* __restrict__ y,
    const float* __restrict__ w_pw, bf16* __restrict__ wpwb) {
  const int t = threadIdx.x;
  if (blockIdx.x >= B_SZ * (L_SEQ / 16)) {
    int i = ((blockIdx.x - B_SZ * (L_SEQ / 16)) * 256 + t) * 8;
    float4 a = *(const float4*)(w_pw + i);
    float4 b = *(const float4*)(w_pw + i + 4);
    union { bf16 h[8]; int4 v; } r;
    r.h[0] = (bf16)a.x; r.h[1] = (bf16)a.y; r.h[2] = (bf16)a.z; r.h[3] = (bf16)a.w;
    r.h[4] = (bf16)b.x; r.h[5] = (bf16)b.y; r.h[6] = (bf16)b.z; r.h[7] = (bf16)b.w;
    *(int4*)(wpwb + i) = r.v;
    return;
  }
  const int b  = blockIdx.x >> 8;     // / (L_SEQ/16 = 256)
  const int l0 = (blockIdx.x & 255) * 16;
  const int d0 = t * 4;
  const float* xb = x + (size_t)b * L_SEQ * D_DIM + d0;
  bf16*        yb = y + (size_t)b * L_SEQ * D_DIM + d0;

  float4 xr[18];
  const float4 zero = make_float4(0.f, 0.f, 0.f, 0.f);
  xr[0] = (l0 >= 2) ? *(const float4*)(xb + (size_t)(l0 - 2) * D_DIM) : zero;
  xr[1] = (l0 >= 1) ? *(const float4*)(xb + (size_t)(l0 - 1) * D_DIM) : zero;
#pragma unroll
  for (int j = 0; j < 16; ++j)
    xr[j + 2] = *(const float4*)(xb + (size_t)(l0 + j) * D_DIM);

  const float* wp = w_dw + d0 * 3;
  float4 wa = *(const float4*)(wp);      // d0:k0,k1,k2  d1:k0
  float4 wb = *(const float4*)(wp + 4);  // d1:k1,k2     d2:k0,k1
  float4 wc = *(const float4*)(wp + 8);  // d2:k2        d3:k0,k1,k2
  float4 bv = *(const float4*)(b_dw + d0);

#pragma unroll
  for (int j = 0; j < 16; ++j) {
    float4 x2 = xr[j], x1 = xr[j + 1], x0 = xr[j + 2];
    float a0 = fmaf(x2.x, wa.x, fmaf(x1.x, wa.y, fmaf(x0.x, wa.z, bv.x)));
    float a1 = fmaf(x2.y, wa.w, fmaf(x1.y, wb.x, fmaf(x0.y, wb.y, bv.y)));
    float a2 = fmaf(x2.z, wb.z, fmaf(x1.z, wb.w, fmaf(x0.z, wc.x, bv.z)));
    float a3 = fmaf(x2.w, wc.y, fmaf(x1.w, wc.z, fmaf(x0.w, wc.w, bv.w)));
    union { bf16 h[4]; int2 v; } o;
    o.h[0] = (bf16)a0; o.h[1] = (bf16)a1; o.h[2] = (bf16)a2; o.h[3] = (bf16)a3;
    *(int2*)(yb + (size_t)(l0 + j) * D_DIM) = o.v;
  }
}

// ---------------------------------------------------------------------------
// Kernel 2: 256x256 8-wave counted-vmcnt GEMM (T3+T4+T5 class).
//   out[m][n] = sum_k y[m][k] * wpwb[n][k] + b_pw[n]
// M=16384, N=1024, K=1024. BM=BN=256, BK=32 -> 32 K-tiles. 512 thr / 8 waves,
// wave tile 128x64 (wmh = wv>>2 m-half, wn = wv&3 n-quarter), acc[8][4].
//
// LDS ring-4: 4 bufs x (A 16KB + B 16KB) = 128 KB. While computing kt we
// stage kt+3 into buf (kt-1)&3 (freed at this kt's start barrier). Stage-to-
// use distance = 3 tile periods (~1200cy) > HBM latency. Counted wait
// s_waitcnt vmcnt(8) once per K-tile (= the 8 loads of kt+1,kt+2 still in
// flight); never 0 in steady state, 4/0 only for the last two tiles.
// NO __syncthreads in the loop — raw s_barrier keeps the DMA queue alive.
//
// Per K-tile, 2 phases, each {ds_read frags; issue 2 gload_lds; sched_barrier;
// s_barrier; setprio(1); 16 MFMA; setprio(0); s_barrier} — ds_read latency
// hides under the barrier / other waves' MFMA (phase role-split => setprio
// has something to arbitrate).
//
// Swizzle (PROVEN in rounds 0/1, ~zero conflicts): 64B row pitch,
//   lds_off(row,c) = row*64 + ((c ^ ((row>>1)&3))<<4) ^ (((row>>2)&1)<<6)
// Write side realized by pre-swizzling the GLOBAL source per slot (LDS dest
// of global_load_lds must stay linear): slot s -> rs=s>>2,
//   grow = rs ^ ((rs>>2)&1), gchunk = (s&3) ^ ((rs>>1)&3).
//
// Epilogue: round-0's proven per-wave LDS transpose (rows 0..34KB of smem,
// disjoint from buf3 which the tail still reads), float4 C stores.
// ---------------------------------------------------------------------------
#define EP_ROWP 68

__global__ __launch_bounds__(512, 2) void gemm256_kernel(
    const bf16* __restrict__ A,   // M x K row-major (y, bf16)
    const bf16* __restrict__ Bm,  // N x K row-major (wpwb, bf16)
    const float* __restrict__ bias, float* __restrict__ C) {
  __shared__ __align__(16) char smem[131072];

  const int t    = threadIdx.x;
  const int m0   = blockIdx.x * 256;  // grid.x = 64 (m) — fastest
  const int n0   = blockIdx.y * 256;  // grid.y = 4 (n)
  const int lane = t & 63;
  const int wv   = t >> 6;
  const int wmh  = wv >> 2;   // 0..1: m-half (128 rows)
  const int wn   = wv & 3;    // 0..3: n-quarter (64 cols)
  const int lrow = lane & 15;
  const int q    = lane >> 4;

  // frag read offsets within a 16KB tile region
  unsigned ra[8], rb[4];
#pragma unroll
  for (int i = 0; i < 8; ++i) {
    int row = wmh * 128 + i * 16 + lrow;
    unsigned a = (unsigned)(row * 64) +
                 ((((unsigned)q) ^ ((unsigned)((row >> 1) & 3))) << 4);
    a ^= ((unsigned)((row >> 2) & 1)) << 6;
    ra[i] = a;
  }
#pragma unroll
  for (int j = 0; j < 4; ++j) {
    int row = wn * 64 + j * 16 + lrow;
    unsigned a = (unsigned)(row * 64) +
                 ((((unsigned)q) ^ ((unsigned)((row >> 1) & 3))) << 4);
    a ^= ((unsigned)((row >> 2) & 1)) << 6;
    rb[j] = a;
  }

  // staging geometry: round r (r=0,1), slot s = r*512 + t
  const bf16* agp[2];
  const bf16* bgp[2];
#pragma unroll
  for (int r = 0; r < 2; ++r) {
    int rs = r * 128 + (t >> 2);
    int grow = rs ^ ((rs >> 2) & 1);
    int gc   = (t & 3) ^ ((rs >> 1) & 3);
    agp[r] = A  + (size_t)(m0 + grow) * D_DIM + gc * 8;
    bgp[r] = Bm + (size_t)(n0 + grow) * D_DIM + gc * 8;
  }
  const unsigned lbase = (unsigned)(wv * 1024);  // wave-uniform LDS base part

  auto stageA = [&](int kt) {
    unsigned bb = (unsigned)((kt & 3) * 32768);
#pragma unroll
    for (int r = 0; r < 2; ++r)
      GLOAD_LDS16(agp[r] + kt * 32, smem + bb + r * 8192 + lbase);
  };
  auto stageB = [&](int kt) {
    unsigned bb = (unsigned)((kt & 3) * 32768 + 16384);
#pragma unroll
    for (int r = 0; r < 2; ++r)
      GLOAD_LDS16(bgp[r] + kt * 32, smem + bb + r * 8192 + lbase);
  };

  f32x4 acc[8][4] = {};

  // prologue: stage tiles 0,1,2 (12 loads/thread outstanding)
  stageA(0); stageB(0);
  stageA(1); stageB(1);
  stageA(2); stageB(2);

  for (int kt = 0; kt < 32; ++kt) {
    // counted drain: kt's 4 loads are the oldest; kt+1/kt+2's 8 may fly on
    if (kt < 30)       asm volatile("s_waitcnt vmcnt(8)" ::: "memory");
    else if (kt == 30) asm volatile("s_waitcnt vmcnt(4)" ::: "memory");
    else               asm volatile("s_waitcnt vmcnt(0)" ::: "memory");
    __builtin_amdgcn_s_barrier();   // buf kt&3 ready; buf (kt-1)&3 now free

    const char* Ab = smem + (size_t)((kt & 3) * 32768);
    const char* Bb = Ab + 16384;

    // ---- phase 0: frags mi0-3 x nj0-3 ----
    bf16x8 af[4], bfr[4], af2[4];
#pragma unroll
    for (int i = 0; i < 4; ++i) af[i]  = *(const bf16x8*)(Ab + ra[i]);
#pragma unroll
    for (int j = 0; j < 4; ++j) bfr[j] = *(const bf16x8*)(Bb + rb[j]);
    if (kt <= 28) stageA(kt + 3);
    __builtin_amdgcn_sched_barrier(0);
    __builtin_amdgcn_s_barrier();
    __builtin_amdgcn_s_setprio(1);
#pragma unroll
    for (int i = 0; i < 4; ++i)
#pragma unroll
      for (int j = 0; j < 4; ++j)
        acc[i][j] = __builtin_amdgcn_mfma_f32_16x16x32_bf16(af[i], bfr[j], acc[i][j], 0, 0, 0);
    __builtin_amdgcn_s_setprio(0);
    __builtin_amdgcn_sched_barrier(0);
    __builtin_amdgcn_s_barrier();

    // ---- phase 1: frags mi4-7 x nj0-3 ----
#pragma unroll
    for (int i = 0; i < 4; ++i) af2[i] = *(const bf16x8*)(Ab + ra[4 + i]);
    if (kt <= 28) stageB(kt + 3);
    __builtin_amdgcn_sched_barrier(0);
    __builtin_amdgcn_s_barrier();
    __builtin_amdgcn_s_setprio(1);
#pragma unroll
    for (int i = 0; i < 4; ++i)
#pragma unroll
      for (int j = 0; j < 4; ++j)
        acc[4 + i][j] = __builtin_amdgcn_mfma_f32_16x16x32_bf16(af2[i], bfr[j], acc[4 + i][j], 0, 0, 0);
    __builtin_amdgcn_s_setprio(0);
    // next kt's vmcnt + start barrier closes this phase
  }

  // --- epilogue: per-wave LDS transpose, then coalesced float4 stores ---
  // ep region = smem[0 .. 34816): bufs 0/1, last read at kt=28/29 — every wave
  // has passed kt=31's barriers, so those reads are long complete.
  float* ep = (float*)smem + (size_t)wv * (16 * EP_ROWP);  // wave-private

  float bvj[4];
#pragma unroll
  for (int j = 0; j < 4; ++j) bvj[j] = bias[n0 + wn * 64 + j * 16 + lrow];

#pragma unroll
  for (int i = 0; i < 8; ++i) {
#pragma unroll
    for (int j = 0; j < 4; ++j)
#pragma unroll
      for (int r = 0; r < 4; ++r)
        ep[(q * 4 + r) * EP_ROWP + j * 16 + lrow] = acc[i][j][r] + bvj[j];
    // wave-private region: in-wave DS program order suffices, no barrier
#pragma unroll
    for (int it2 = 0; it2 < 4; ++it2) {
      int flat = it2 * 64 + lane;
      int row  = flat >> 4;
      int c16  = flat & 15;
      float4 v = *(const float4*)(ep + row * EP_ROWP + c16 * 4);
      int gm = m0 + wmh * 128 + i * 16 + row;
      int gn = n0 + wn * 64 + c16 * 4;
      *(float4*)(C + (size_t)gm * D_DIM + gn) = v;
    }
  }
}

// ---------------------------------------------------------------------------
// Fallback (only if workspace is too small): correct but slow fp32 path.
// ---------------------------------------------------------------------------
__global__ __launch_bounds__(256) void fallback_kernel(
    const float* __restrict__ x, const float* __restrict__ w_dw,
    const float* __restrict__ b_dw, const float* __restrict__ w_pw,
    const float* __restrict__ b_pw, float* __restrict__ out) {
  __shared__ float ys[D_DIM];
  const int m = blockIdx.x;
  const int l = m & (L_SEQ - 1);
  const int t = threadIdx.x;
  const float* xr = x + (size_t)m * D_DIM;
#pragma unroll
  for (int c = 0; c < 4; ++c) {
    int d = t + c * 256;
    float a = fmaf(xr[d], w_dw[d * 3 + 2], b_dw[d]);
    if (l >= 1) a = fmaf(xr[d - D_DIM], w_dw[d * 3 + 1], a);
    if (l >= 2) a = fmaf(xr[d - 2 * D_DIM], w_dw[d * 3 + 0], a);
    ys[d] = a;
  }
  __syncthreads();
#pragma unroll
  for (int c = 0; c < 4; ++c) {
    int e = t + c * 256;
    const float* wr = w_pw + (size_t)e * D_DIM;
    float a = b_pw[e];
    for (int d = 0; d < D_DIM; ++d) a = fmaf(ys[d], wr[d], a);
    out[(size_t)m * D_DIM + e] = a;
  }
}

extern "C" void kernel_launch(void* const* d_in, const int* in_sizes, int n_in,
                              void* d_out, int out_size, void* d_ws, size_t ws_size,
                              hipStream_t stream) {
  (void)in_sizes; (void)n_in; (void)out_size;
  const float* x    = (const float*)d_in[0];
  const float* w_dw = (const float*)d_in[1];
  const float* b_dw = (const float*)d_in[2];
  const float* w_pw = (const float*)d_in[3];
  const float* b_pw = (const float*)d_in[4];
  float* out = (float*)d_out;

  const size_t y_elems = (size_t)M_TOT * D_DIM;          // 16M bf16 = 32 MB
  const size_t w_elems = (size_t)D_DIM * D_DIM;          // 1M bf16  =  2 MB
  const size_t need = (y_elems + w_elems) * sizeof(bf16);

  if (ws_size >= need) {
    bf16* y    = (bf16*)d_ws;
    bf16* wpwb = (bf16*)d_ws + y_elems;
    const int dw_blocks  = B_SZ * (L_SEQ / 16);          // 1024
    const int cvt_blocks = (D_DIM * D_DIM / 8) / 256;    // 512
    dw_bf16_kernel<<<dw_blocks + cvt_blocks, 256, 0, stream>>>(x, w_dw, b_dw, y, w_pw, wpwb);
    dim3 grid(M_TOT / 256, D_DIM / 256);                 // (64, 4): m fastest
    gemm256_kernel<<<grid, 512, 0, stream>>>(y, wpwb, b_pw, out);
  } else {
    fallback_kernel<<<M_TOT, 256, 0, stream>>>(x, w_dw, b_dw, w_pw, b_pw, out);
  }
}